// Round 1
// baseline (396.063 us; speedup 1.0000x reference)
//
#include <hip/hip_runtime.h>

#define N_NODES 100000
#define N_EDGES 3200000
#define IN_FEATS 256
#define N_HEADS 8
#define OUT_FEATS 32
#define NEG_SLOPE 0.2f

// d_ws layout:
//   [0, 16384)                 : wlr [256][16]  (folded W*attn, el cols 0-7, er cols 8-15)
//   [16384, 16384+6.4MB)       : elr [N_NODES][16]  (el heads 0-7, er heads 8-15)
//   [+ , +3.2MB)               : ssum [N_NODES][8]  (softmax denominators)

// ---- kernel 1: fold W with attn_l/attn_r -> wlr[256][16] ----
__global__ void k_wlr(const float* __restrict__ W, const float* __restrict__ al,
                      const float* __restrict__ ar, float* __restrict__ wlr) {
    int t = blockIdx.x * blockDim.x + threadIdx.x;   // 4096 threads
    if (t >= 256 * 16) return;
    int k = t >> 4, j = t & 15;
    int h = j & 7;
    const float* av = (j < 8) ? al : ar;             // attn [8][32]
    const float* wrow = W + k * 256 + h * 32;
    float s = 0.f;
#pragma unroll
    for (int f = 0; f < 32; ++f) s += wrow[f] * av[h * 32 + f];
    wlr[k * 16 + j] = s;
}

// ---- kernel 2: elr = feat @ wlr, one wave per row, grid-stride ----
__global__ void __launch_bounds__(256) k_elr(const float* __restrict__ feat,
                                             const float* __restrict__ wlr,
                                             float* __restrict__ elr) {
    int lane = threadIdx.x & 63;
    int gwave = (blockIdx.x * blockDim.x + threadIdx.x) >> 6;
    int nwaves = (gridDim.x * blockDim.x) >> 6;

    // per-lane weights: 4 k-rows x 16 outputs = 64 regs, loaded once
    float w[4][16];
#pragma unroll
    for (int i = 0; i < 4; ++i) {
#pragma unroll
        for (int j4 = 0; j4 < 4; ++j4) {
            float4 v = *(const float4*)(wlr + (lane * 4 + i) * 16 + j4 * 4);
            w[i][j4 * 4 + 0] = v.x; w[i][j4 * 4 + 1] = v.y;
            w[i][j4 * 4 + 2] = v.z; w[i][j4 * 4 + 3] = v.w;
        }
    }

    for (int row = gwave; row < N_NODES; row += nwaves) {
        float4 f4 = *(const float4*)(feat + row * 256 + lane * 4);
        float acc[16];
#pragma unroll
        for (int j = 0; j < 16; ++j)
            acc[j] = f4.x * w[0][j] + f4.y * w[1][j] + f4.z * w[2][j] + f4.w * w[3][j];
        // 64-lane butterfly all-reduce of 16 values
#pragma unroll
        for (int m = 1; m < 64; m <<= 1) {
#pragma unroll
            for (int j = 0; j < 16; ++j)
                acc[j] += __shfl_xor(acc[j], m, 64);
        }
        if (lane == 0) {
            float4* o = (float4*)(elr + row * 16);
            o[0] = make_float4(acc[0], acc[1], acc[2], acc[3]);
            o[1] = make_float4(acc[4], acc[5], acc[6], acc[7]);
            o[2] = make_float4(acc[8], acc[9], acc[10], acc[11]);
            o[3] = make_float4(acc[12], acc[13], acc[14], acc[15]);
        }
    }
}

// ---- kernel 3: accumulate softmax denominators (no max-subtraction; see analysis) ----
__global__ void k_expsum(const int* __restrict__ src, const int* __restrict__ dst,
                         const float* __restrict__ elr, float* __restrict__ ssum) {
    int t = blockIdx.x * 256 + threadIdx.x;          // t < E*8 = 25.6M
    int e = t >> 3, h = t & 7;
    int sn = src[e], dn = dst[e];
    float v = elr[sn * 16 + h] + elr[dn * 16 + 8 + h];
    v = v > 0.f ? v : NEG_SLOPE * v;
    atomicAdd(ssum + dn * 8 + h, __expf(v));
}

// ---- kernel 4: recompute exp and normalize, write output [E][8] ----
__global__ void k_norm(const int* __restrict__ src, const int* __restrict__ dst,
                       const float* __restrict__ elr, const float* __restrict__ ssum,
                       float* __restrict__ out) {
    int t = blockIdx.x * 256 + threadIdx.x;
    int e = t >> 3, h = t & 7;
    int sn = src[e], dn = dst[e];
    float v = elr[sn * 16 + h] + elr[dn * 16 + 8 + h];
    v = v > 0.f ? v : NEG_SLOPE * v;
    out[t] = __expf(v) / ssum[dn * 8 + h];
}

extern "C" void kernel_launch(void* const* d_in, const int* in_sizes, int n_in,
                              void* d_out, int out_size, void* d_ws, size_t ws_size,
                              hipStream_t stream) {
    const float* feat = (const float*)d_in[0];
    const float* W    = (const float*)d_in[1];
    const float* al   = (const float*)d_in[2];
    const float* ar   = (const float*)d_in[3];
    const int*   src  = (const int*)d_in[4];
    const int*   dst  = (const int*)d_in[5];
    float* out = (float*)d_out;

    char* ws = (char*)d_ws;
    float* wlr  = (float*)ws;                                    // 16 KB
    float* elr  = (float*)(ws + 16384);                          // 6.4 MB
    float* ssum = (float*)(ws + 16384 + (size_t)N_NODES * 16 * 4); // 3.2 MB

    // zero the denominators every call (atomic accumulation target)
    hipMemsetAsync(ssum, 0, (size_t)N_NODES * 8 * 4, stream);

    k_wlr<<<16, 256, 0, stream>>>(W, al, ar, wlr);
    k_elr<<<2048, 256, 0, stream>>>(feat, wlr, elr);

    int nthreads = N_EDGES * 8;                  // 25.6M
    int nblk = nthreads / 256;                   // 100000, exact
    k_expsum<<<nblk, 256, 0, stream>>>(src, dst, elr, ssum);
    k_norm<<<nblk, 256, 0, stream>>>(src, dst, elr, ssum, out);
}